// Round 7
// baseline (102677.344 us; speedup 1.0000x reference)
//
#include <hip/hip_runtime.h>

#define S_LEN 256
#define BATCH 256
#define EDIM 512
#define HDIM 1024
#define LDS_BYTES 131072   // 16 resident Wh k-tiles * 8 KB

typedef short short8 __attribute__((ext_vector_type(8)));
typedef float f32x4 __attribute__((ext_vector_type(4)));
typedef unsigned long long u64;
typedef unsigned short us;

__device__ __forceinline__ us f2bf(float f) {
  unsigned u = __float_as_uint(f);
  u = u + 0x7FFFu + ((u >> 16) & 1u);   // RNE
  return (us)(u >> 16);
}
__device__ __forceinline__ float bf2f(us s) {
  return __uint_as_float(((unsigned)s) << 16);
}
__device__ __forceinline__ float sigf(float x) { return 1.0f / (1.0f + __expf(-x)); }
__device__ __forceinline__ float tanh_(float x) { return 2.0f / (1.0f + __expf(-2.0f * x)) - 1.0f; }

#define MFMA(d, a, b) d = __builtin_amdgcn_mfma_f32_16x16x32_bf16(a, b, d, 0, 0, 0)

// Coherent (agent) 16B frag load: two 8B agent-scope relaxed atomic loads (R0-proven).
// These bypass L1/L2 and are MALL/L3-served -> deepening their prefetch cannot
// thrash caches (R4: 16.8 GB h-reads -> only 0.8 GB HBM fetch).
__device__ __forceinline__ short8 load_hfrag(const us* p) {
  union { u64 d[2]; short8 v; } u;
  u.d[0] = __hip_atomic_load((const u64*)p,       __ATOMIC_RELAXED, __HIP_MEMORY_SCOPE_AGENT);
  u.d[1] = __hip_atomic_load((const u64*)(p + 4), __ATOMIC_RELAXED, __HIP_MEMORY_SCOPE_AGENT);
  return u.v;
}
__device__ __forceinline__ short8 ldf(const us* p) {  // plain 16B frag load
  union { uint4 d; short8 v; } u;
  u.d = *(const uint4*)p;
  return u.v;
}

// All frag units are LANE-LINEAR: unit = 512 shorts (1 KB); lane l's 16 bytes at l*16.

// ---------------- Phase 1: gather -> Xf[s][kt16][btile16][512] ----------------
__global__ void gather_embed(const int* __restrict__ inputs, const float* __restrict__ emb,
                             us* __restrict__ Xf) {
  int T = blockIdx.x * 256 + threadIdx.x;   // 1,048,576
  int kt = T & 15;
  int b  = (T >> 4) & 255;
  int s  = T >> 12;
  int vid = inputs[b * S_LEN + s];
  const float* src = emb + (size_t)vid * EDIM + kt * 32;
  int c = b & 15;
  us* ub = Xf + ((size_t)(s * 16 + kt) * 16 + (b >> 4)) * 512;
#pragma unroll
  for (int q = 0; q < 4; ++q) {
    float4 v0 = *(const float4*)(src + q * 8);
    float4 v1 = *(const float4*)(src + q * 8 + 4);
    us o[8] = { f2bf(v0.x), f2bf(v0.y), f2bf(v0.z), f2bf(v0.w),
                f2bf(v1.x), f2bf(v1.y), f2bf(v1.z), f2bf(v1.w) };
    *(uint4*)(ub + (size_t)(c + 16 * q) * 8) = *(const uint4*)o;
  }
}

// ---------------- Phase 2: pack W into lane-linear frag units ----------------
__global__ void pack_w(const float* __restrict__ Wx_f, const float* __restrict__ Wh_f,
                       const float* __restrict__ Wx_b, const float* __restrict__ Wh_b,
                       us* __restrict__ Wxp, us* __restrict__ Whp) {
  int T = blockIdx.x * 256 + threadIdx.x;   // 1,572,864
  int c = T & 15;
  int q = (T >> 4) & 3;
  int t = (T >> 6) & 7;
  int r = T >> 9;                           // 0..3071
  int kit = r % 48;
  int jbd = r / 48;
  int jb  = jbd & 31;
  int dir = jbd >> 5;
  int g = t >> 1, h16 = t & 1;
  int n = g * 1024 + jb * 32 + h16 * 16 + c;
  const float* W; int k0;
  if (kit < 16) { W = dir ? Wx_b : Wx_f; k0 = kit * 32 + q * 8; }
  else          { W = dir ? Wh_b : Wh_f; k0 = (kit - 16) * 32 + q * 8; }
  us o[8];
#pragma unroll
  for (int e = 0; e < 8; ++e) o[e] = f2bf(W[(size_t)(k0 + e) * 4096 + n]);
  us* dst;
  if (kit < 16) dst = Wxp + (((size_t)(dir * 32 + jb) * 16 + kit) * 8 + t) * 512;
  else          dst = Whp + (((size_t)(dir * 32 + jb) * 32 + (kit - 16)) * 8 + t) * 512;
  *(uint4*)(dst + (size_t)(c + 16 * q) * 8) = *(const uint4*)o;
}

// ---------------- Phase 3: persistent BiLSTM, 8 waves/block ----------------
// R4 structure (passed, 4650 us) with ONE change: h-part A-prefetch depth 4->8.
// h loads are agent-scope (cache-bypassing, MALL-served) so deeper prefetch is
// cache-safe; x-part and all B-streams keep R4's tight compiler window (R5
// proved wide X/W rings thrash L1 -> 26x HBM fetch). MFMA order unchanged.
__global__ __launch_bounds__(512, 1) void lstm_main(
    const us* __restrict__ Xf,
    const us* __restrict__ Wxp,
    const us* __restrict__ Whp,
    const float* __restrict__ bias_f,
    const float* __restrict__ bias_b,
    us* __restrict__ Hf,                    // [buf2][dir2][kt32][btile16][512]
    unsigned int* __restrict__ slots)       // [group8][32][16]
{
  extern __shared__ __align__(16) unsigned char smem[];

  const int bx   = blockIdx.x;
  const int xcd  = bx & 7;
  const int dir  = xcd >> 2;
  const int joct = xcd & 3;
  const int rr   = bx >> 3;           // 0..31
  const int jb   = joct * 8 + (rr & 7);
  const int mq   = rr >> 3;

  const int tid  = threadIdx.x;
  const int wave = tid >> 6;          // 0..7
  const int lane = tid & 63;
  const int mw   = wave & 3;          // btile within the block's 4
  const int nw   = wave >> 2;         // col half (16 cols each)
  const int c    = lane & 15;
  const int q    = lane >> 4;
  const int lofs = lane * 8;          // shorts (16 B)

  // one-time LDS fill: Whp units (dir,jb), hk 16..31 -> 8192 uint4, linear
  {
    const uint4* src = (const uint4*)(Whp + (((size_t)(dir * 32 + jb) * 32 + 16) * 8) * 512);
    for (int i = tid; i < 8192; i += 512) *(uint4*)(smem + (size_t)i * 16) = src[i];
  }
  const float* bias = dir ? bias_b : bias_f;
  const int j = jb * 32 + nw * 16 + c;
  float bg[4];
#pragma unroll
  for (int g = 0; g < 4; ++g) bg[g] = bias[g * HDIM + j];
  __syncthreads();

  unsigned int* grp_slots = slots + (dir * 4 + mq) * (32 * 16);
  unsigned int* my_slot   = grp_slots + jb * 16;

  const int bt0 = mq * 4 + mw;        // this wave's single btile
  const us* xu_base  = Xf + (size_t)bt0 * 512 + lofs;
  const us* wxu = Wxp + (((size_t)(dir * 32 + jb) * 16) * 8 + nw) * 512 + lofs;
  const us* whu = Whp + (((size_t)(dir * 32 + jb) * 32) * 8 + nw) * 512 + lofs;
  const int ldsofs = (nw * 512 + lane * 8) * 2;   // + g*2048 + hk*8192 bytes

  float c_reg[4] = {0.f, 0.f, 0.f, 0.f};

  for (int s = 0; s < S_LEN; ++s) {
    const int sx = dir ? (S_LEN - 1 - s) : s;
    const int p  = s & 1;

    f32x4 acc[4];
#pragma unroll
    for (int g = 0; g < 4; ++g)
      acc[g] = (f32x4){bg[g], bg[g], bg[g], bg[g]};

    // ---- x-part (no h dependency; runs before the wait) ---- [EXACT R4]
    {
      const us* xu = xu_base + (size_t)sx * (16 * 16 * 512);
#pragma unroll 4
      for (int k = 0; k < 16; ++k) {
        short8 a0 = ldf(xu + (size_t)k * 8192);
        const us* wb = wxu + (size_t)k * 4096;
        short8 b0 = ldf(wb);
        short8 b1 = ldf(wb + 1024);
        short8 b2 = ldf(wb + 2048);
        short8 b3 = ldf(wb + 3072);
        MFMA(acc[0], a0, b0); MFMA(acc[1], a0, b1);
        MFMA(acc[2], a0, b2); MFMA(acc[3], a0, b3);
      }
    }

    // ---- wait for h_s: lanes 0..31 poll the 32 producer slots of own group ----
    if (s > 0) {
      if (tid < 32) {
        const unsigned int* sl = grp_slots + tid * 16;
        for (;;) {
          unsigned v = __hip_atomic_load(sl, __ATOMIC_RELAXED, __HIP_MEMORY_SCOPE_AGENT);
          if (!__any(v < (unsigned)s)) break;
          __builtin_amdgcn_s_sleep(1);
        }
      }
      __syncthreads();
      asm volatile("" ::: "memory");
    }

    // ---- h-part: A coherent from Hf (prefetch depth 8); B: streamed hk 0..15, LDS hk 16..31 ----
    {
      const us* hu = Hf + (((size_t)(p * 2 + dir) * 32) * 16 + bt0) * 512 + lofs;
      short8 pa[8];
#pragma unroll
      for (int i = 0; i < 8; ++i) pa[i] = load_hfrag(hu + (size_t)i * 8192);
#pragma unroll 4
      for (int k = 0; k < 16; ++k) {
        short8 a0 = pa[k & 7];
        pa[k & 7] = load_hfrag(hu + (size_t)(k + 8) * 8192);
        const us* wb = whu + (size_t)k * 4096;
        short8 b0 = ldf(wb);
        short8 b1 = ldf(wb + 1024);
        short8 b2 = ldf(wb + 2048);
        short8 b3 = ldf(wb + 3072);
        MFMA(acc[0], a0, b0); MFMA(acc[1], a0, b1);
        MFMA(acc[2], a0, b2); MFMA(acc[3], a0, b3);
      }
#pragma unroll 4
      for (int k = 16; k < 24; ++k) {
        short8 a0 = pa[k & 7];
        pa[k & 7] = load_hfrag(hu + (size_t)(k + 8) * 8192);
        const unsigned char* lb = smem + (size_t)(k - 16) * 8192 + ldsofs;
        short8 b0 = *(const short8*)(lb);
        short8 b1 = *(const short8*)(lb + 2048);
        short8 b2 = *(const short8*)(lb + 4096);
        short8 b3 = *(const short8*)(lb + 6144);
        MFMA(acc[0], a0, b0); MFMA(acc[1], a0, b1);
        MFMA(acc[2], a0, b2); MFMA(acc[3], a0, b3);
      }
#pragma unroll
      for (int k = 24; k < 32; ++k) {
        short8 a0 = pa[k & 7];
        const unsigned char* lb = smem + (size_t)(k - 16) * 8192 + ldsofs;
        short8 b0 = *(const short8*)(lb);
        short8 b1 = *(const short8*)(lb + 2048);
        short8 b2 = *(const short8*)(lb + 4096);
        short8 b3 = *(const short8*)(lb + 6144);
        MFMA(acc[0], a0, b0); MFMA(acc[1], a0, b1);
        MFMA(acc[2], a0, b2); MFMA(acc[3], a0, b3);
      }
    }

    // ---- gate combine in registers; coherent h stores (one btile per wave) ----
    {
      const int q2 = nw * 2 + (c >> 3);
      const int e2 = c & 7;
      const size_t ob = ((size_t)(((p ^ 1) * 2 + dir) * 32 + jb) * 16 + bt0) * 512;
      us* hd = Hf + ob + (size_t)(16 * q2) * 8 + e2;
#pragma unroll
      for (int rg = 0; rg < 4; ++rg) {
        float gi = acc[0][rg], gf = acc[1][rg];
        float go = acc[2][rg], gc = acc[3][rg];
        float cn = sigf(gf) * c_reg[rg] + sigf(gi) * tanh_(gc);
        c_reg[rg] = cn;
        __hip_atomic_store(hd + (size_t)(q * 4 + rg) * 8, f2bf(sigf(go) * tanh_(cn)),
                           __ATOMIC_RELAXED, __HIP_MEMORY_SCOPE_AGENT);
      }
    }
    asm volatile("s_waitcnt vmcnt(0)" ::: "memory");
    __syncthreads();
    if (tid == 0)
      __hip_atomic_store(my_slot, (unsigned)(s + 1), __ATOMIC_RELAXED, __HIP_MEMORY_SCOPE_AGENT);
  }
}

// ---------------- Phase 4: logits + softmax, one block per batch row ----------------
__global__ void final_softmax(const us* __restrict__ Hf,  // buf 0
                              const float* __restrict__ Whq,
                              const float* __restrict__ bq,
                              float* __restrict__ out) {
  __shared__ float red[4][10];
  const int b = blockIdx.x;
  const int tid = threadIdx.x;
  float acc[10];
#pragma unroll
  for (int qq = 0; qq < 10; ++qq) acc[qq] = 0.f;
#pragma unroll
  for (int u = 0; u < 4; ++u) {
    int j = tid * 4 + u;
    int kt = j >> 5, q2 = (j & 31) >> 3, e = j & 7;
    size_t idx = (((size_t)kt * 16 + (b >> 4)) * 512) + ((size_t)((b & 15) + 16 * q2)) * 8 + e;
    float xv = bf2f(Hf[idx]) + bf2f(Hf[(size_t)32 * 16 * 512 + idx]);
#pragma unroll
    for (int qq = 0; qq < 10; ++qq) acc[qq] += xv * Whq[j * 10 + qq];
  }
#pragma unroll
  for (int qq = 0; qq < 10; ++qq)
#pragma unroll
    for (int off = 32; off; off >>= 1) acc[qq] += __shfl_down(acc[qq], off, 64);
  if ((tid & 63) == 0)
#pragma unroll
    for (int qq = 0; qq < 10; ++qq) red[tid >> 6][qq] = acc[qq];
  __syncthreads();
  if (tid == 0) {
    float t[10];
#pragma unroll
    for (int qq = 0; qq < 10; ++qq)
      t[qq] = red[0][qq] + red[1][qq] + red[2][qq] + red[3][qq] + bq[qq];
    float mx = t[0];
#pragma unroll
    for (int qq = 1; qq < 10; ++qq) mx = fmaxf(mx, t[qq]);
    float sum = 0.f;
#pragma unroll
    for (int qq = 0; qq < 10; ++qq) { t[qq] = __expf(t[qq] - mx); sum += t[qq]; }
    float inv = 1.0f / sum;
#pragma unroll
    for (int qq = 0; qq < 10; ++qq) out[b * 10 + qq] = t[qq] * inv;
  }
}

extern "C" void kernel_launch(void* const* d_in, const int* in_sizes, int n_in,
                              void* d_out, int out_size, void* d_ws, size_t ws_size,
                              hipStream_t stream) {
  const int*   inputs = (const int*)d_in[0];
  const float* emb    = (const float*)d_in[1];
  const float* Wx_f   = (const float*)d_in[2];
  const float* Wh_f   = (const float*)d_in[3];
  const float* b_f    = (const float*)d_in[4];
  const float* Wx_b   = (const float*)d_in[5];
  const float* Wh_b   = (const float*)d_in[6];
  const float* b_b    = (const float*)d_in[7];
  const float* W_hq   = (const float*)d_in[8];
  const float* b_q    = (const float*)d_in[9];
  float* out = (float*)d_out;

  char* ws = (char*)d_ws;
  us* Xf  = (us*)ws;                              // 64 MiB
  us* Wxp = (us*)(ws + (64ull << 20));            //  8 MiB
  us* Whp = (us*)(ws + (72ull << 20));            // 16 MiB
  us* Hf  = (us*)(ws + (88ull << 20));            //  2 MiB
  unsigned int* slt = (unsigned int*)(ws + (90ull << 20));  // 16 KiB

  hipMemsetAsync(Hf, 0, (size_t)2 * 2 * 32 * 16 * 512 * sizeof(us), stream);
  hipMemsetAsync(slt, 0, 8 * 32 * 16 * sizeof(unsigned int), stream);

  gather_embed<<<4096, 256, 0, stream>>>(inputs, emb, Xf);
  pack_w<<<6144, 256, 0, stream>>>(Wx_f, Wh_f, Wx_b, Wh_b, Wxp, Whp);

  hipFuncSetAttribute((const void*)lstm_main,
                      hipFuncAttributeMaxDynamicSharedMemorySize, LDS_BYTES);

  const us* xf_p = Xf;
  const us* wxp_p = Wxp;
  const us* whp_p = Whp;
  const float* bf_p = b_f;
  const float* bb_p = b_b;
  us* hf_p = Hf;
  unsigned int* slt_p = slt;
  void* kargs[] = { (void*)&xf_p, (void*)&wxp_p, (void*)&whp_p, (void*)&bf_p,
                    (void*)&bb_p, (void*)&hf_p, (void*)&slt_p };
  hipLaunchCooperativeKernel((void*)lstm_main, dim3(256), dim3(512), kargs, LDS_BYTES, stream);

  // final h (after step 256) lives in buf 0
  final_softmax<<<256, 256, 0, stream>>>(Hf, W_hq, b_q, out);
}

// Round 8
// 4713.787 us; speedup vs baseline: 21.7823x; 21.7823x over previous
//
#include <hip/hip_runtime.h>

#define S_LEN 256
#define BATCH 256
#define EDIM 512
#define HDIM 1024
#define LDS_BYTES 131072   // FULL Wh slice: 32 hk x 4 gates x 1 KB = 128 KB

typedef short short8 __attribute__((ext_vector_type(8)));
typedef float f32x4 __attribute__((ext_vector_type(4)));
typedef unsigned long long u64;
typedef unsigned short us;

__device__ __forceinline__ us f2bf(float f) {
  unsigned u = __float_as_uint(f);
  u = u + 0x7FFFu + ((u >> 16) & 1u);   // RNE
  return (us)(u >> 16);
}
__device__ __forceinline__ float bf2f(us s) {
  return __uint_as_float(((unsigned)s) << 16);
}
__device__ __forceinline__ float sigf(float x) { return 1.0f / (1.0f + __expf(-x)); }
__device__ __forceinline__ float tanh_(float x) { return 2.0f / (1.0f + __expf(-2.0f * x)) - 1.0f; }

#define MFMA(d, a, b) d = __builtin_amdgcn_mfma_f32_16x16x32_bf16(a, b, d, 0, 0, 0)

// Coherent (agent) 16B frag load: two 8B agent-scope relaxed atomic loads (R0-proven).
__device__ __forceinline__ short8 load_hfrag(const us* p) {
  union { u64 d[2]; short8 v; } u;
  u.d[0] = __hip_atomic_load((const u64*)p,       __ATOMIC_RELAXED, __HIP_MEMORY_SCOPE_AGENT);
  u.d[1] = __hip_atomic_load((const u64*)(p + 4), __ATOMIC_RELAXED, __HIP_MEMORY_SCOPE_AGENT);
  return u.v;
}
__device__ __forceinline__ short8 ldf(const us* p) {  // plain 16B frag load
  union { uint4 d; short8 v; } u;
  u.d = *(const uint4*)p;
  return u.v;
}

// All frag units are LANE-LINEAR: unit = 512 shorts (1 KB); lane l's 16 bytes at l*16.

// ---------------- Phase 1: gather -> Xf[s][kt16][btile16][512] ----------------
__global__ void gather_embed(const int* __restrict__ inputs, const float* __restrict__ emb,
                             us* __restrict__ Xf) {
  int T = blockIdx.x * 256 + threadIdx.x;   // 1,048,576
  int kt = T & 15;
  int b  = (T >> 4) & 255;
  int s  = T >> 12;
  int vid = inputs[b * S_LEN + s];
  const float* src = emb + (size_t)vid * EDIM + kt * 32;
  int c = b & 15;
  us* ub = Xf + ((size_t)(s * 16 + kt) * 16 + (b >> 4)) * 512;
#pragma unroll
  for (int q = 0; q < 4; ++q) {
    float4 v0 = *(const float4*)(src + q * 8);
    float4 v1 = *(const float4*)(src + q * 8 + 4);
    us o[8] = { f2bf(v0.x), f2bf(v0.y), f2bf(v0.z), f2bf(v0.w),
                f2bf(v1.x), f2bf(v1.y), f2bf(v1.z), f2bf(v1.w) };
    *(uint4*)(ub + (size_t)(c + 16 * q) * 8) = *(const uint4*)o;
  }
}

// ---------------- Phase 2: pack W into lane-linear frag units ----------------
__global__ void pack_w(const float* __restrict__ Wx_f, const float* __restrict__ Wh_f,
                       const float* __restrict__ Wx_b, const float* __restrict__ Wh_b,
                       us* __restrict__ Wxp, us* __restrict__ Whp) {
  int T = blockIdx.x * 256 + threadIdx.x;   // 1,572,864
  int c = T & 15;
  int q = (T >> 4) & 3;
  int t = (T >> 6) & 7;
  int r = T >> 9;                           // 0..3071
  int kit = r % 48;
  int jbd = r / 48;
  int jb  = jbd & 31;
  int dir = jbd >> 5;
  int g = t >> 1, h16 = t & 1;
  int n = g * 1024 + jb * 32 + h16 * 16 + c;
  const float* W; int k0;
  if (kit < 16) { W = dir ? Wx_b : Wx_f; k0 = kit * 32 + q * 8; }
  else          { W = dir ? Wh_b : Wh_f; k0 = (kit - 16) * 32 + q * 8; }
  us o[8];
#pragma unroll
  for (int e = 0; e < 8; ++e) o[e] = f2bf(W[(size_t)(k0 + e) * 4096 + n]);
  us* dst;
  if (kit < 16) dst = Wxp + (((size_t)(dir * 32 + jb) * 16 + kit) * 8 + t) * 512;
  else          dst = Whp + (((size_t)(dir * 32 + jb) * 32 + (kit - 16)) * 8 + t) * 512;
  *(uint4*)(dst + (size_t)(c + 16 * q) * 8) = *(const uint4*)o;
}

// ---------------- Phase 3: persistent BiLSTM, Wh fully LDS-resident ----------------
// Re-tile vs R4: 256 blocks = 2 dir x 2 mq x 64 J. Block owns 16 h-cols
// (J -> kt unit jt=J>>1, half jh=J&1) and 8 btiles (one per wave, bt0=mq*8+wave).
// Wh slice (1024 x 64 cols) = 128 KB sits ENTIRELY in LDS -> zero per-step Wh
// stream (was 128 KB/step x4 wave-dup from L2). Wx slice = 64 KB/step, shared
// by all 8 waves (4 KB/k-iter -> L1-served). h A-ring stays at proven depth 4.
// Ring: 4 groups (dir,mq) x 64 producers; one full wave (64 lanes) polls.
// MFMA accumulation order per output element is IDENTICAL to R0/R4.
__global__ __launch_bounds__(512, 1) void lstm_main(
    const us* __restrict__ Xf,
    const us* __restrict__ Wxp,
    const us* __restrict__ Whp,
    const float* __restrict__ bias_f,
    const float* __restrict__ bias_b,
    us* __restrict__ Hf,                    // [buf2][dir2][kt32][btile16][512]
    unsigned int* __restrict__ slots)       // [group4][64][16]
{
  extern __shared__ __align__(16) unsigned char smem[];

  const int bx  = blockIdx.x;
  const int dir = bx & 1;
  const int mq  = (bx >> 1) & 1;
  const int J   = bx >> 2;            // 0..63
  const int jh  = J & 1;              // half within kt unit (cols jh*16..+16)
  const int jt  = J >> 1;             // kt unit / old jb (0..31)

  const int tid  = threadIdx.x;
  const int wave = tid >> 6;          // 0..7 -> btile
  const int lane = tid & 63;
  const int c    = lane & 15;
  const int q    = lane >> 4;
  const int lofs = lane * 8;          // shorts (16 B)

  // LDS fill: Wh units for (dir, jt, jh), all 32 hk x 4 gates, layout [hk][g][1KB]
  // i = hk*256 + g*64 + within  (uint4 units; 8192 total = 128 KB)
  {
    const uint4* W4 = (const uint4*)Whp;
    for (int i = tid; i < 8192; i += 512) {
      int within = i & 63;
      int g  = (i >> 6) & 3;
      int hk = i >> 8;
      size_t src = ((((size_t)(dir * 32 + jt) * 32 + hk) * 8) + (g * 2 + jh)) * 64 + within;
      *(uint4*)(smem + (size_t)i * 16) = W4[src];
    }
  }
  const float* bias = dir ? bias_b : bias_f;
  const int j = J * 16 + c;
  float bg[4];
#pragma unroll
  for (int g = 0; g < 4; ++g) bg[g] = bias[g * HDIM + j];
  __syncthreads();

  unsigned int* grp_slots = slots + (dir * 2 + mq) * (64 * 16);
  unsigned int* my_slot   = grp_slots + J * 16;

  const int bt0 = mq * 8 + wave;      // this wave's single btile
  const us* xu_base = Xf + (size_t)bt0 * 512 + lofs;
  const us* wxu = Wxp + ((size_t)(dir * 32 + jt) * 16) * 8 * 512 + (size_t)jh * 512 + lofs;
  const unsigned char* lbbase = smem + (size_t)lane * 16;

  float c_reg[4] = {0.f, 0.f, 0.f, 0.f};

  for (int s = 0; s < S_LEN; ++s) {
    const int sx = dir ? (S_LEN - 1 - s) : s;
    const int p  = s & 1;

    f32x4 acc[4];
#pragma unroll
    for (int g = 0; g < 4; ++g)
      acc[g] = (f32x4){bg[g], bg[g], bg[g], bg[g]};

    // ---- x-part (no h dependency; runs before the wait) ----
    {
      const us* xu = xu_base + (size_t)sx * (16 * 16 * 512);
#pragma unroll 4
      for (int k = 0; k < 16; ++k) {
        short8 a0 = ldf(xu + (size_t)k * 8192);
        const us* wb = wxu + (size_t)k * 4096;
        short8 b0 = ldf(wb);
        short8 b1 = ldf(wb + 1024);
        short8 b2 = ldf(wb + 2048);
        short8 b3 = ldf(wb + 3072);
        MFMA(acc[0], a0, b0); MFMA(acc[1], a0, b1);
        MFMA(acc[2], a0, b2); MFMA(acc[3], a0, b3);
      }
    }

    // ---- wait for h_s: 64 lanes poll the 64 producer slots of own group ----
    if (s > 0) {
      if (tid < 64) {
        const unsigned int* sl = grp_slots + tid * 16;
        for (;;) {
          unsigned v = __hip_atomic_load(sl, __ATOMIC_RELAXED, __HIP_MEMORY_SCOPE_AGENT);
          if (!__any(v < (unsigned)s)) break;
          __builtin_amdgcn_s_sleep(1);
        }
      }
      __syncthreads();
      asm volatile("" ::: "memory");
    }

    // ---- h-part: A coherent from Hf (proven depth-4 ring); B entirely from LDS ----
    {
      const us* hu = Hf + (((size_t)(p * 2 + dir) * 32) * 16 + bt0) * 512 + lofs;
      short8 pa[4];
#pragma unroll
      for (int i = 0; i < 4; ++i) pa[i] = load_hfrag(hu + (size_t)i * 8192);
#pragma unroll 4
      for (int k = 0; k < 28; ++k) {
        short8 a0 = pa[k & 3];
        pa[k & 3] = load_hfrag(hu + (size_t)(k + 4) * 8192);
        const unsigned char* lb = lbbase + (size_t)k * 4096;
        short8 b0 = *(const short8*)(lb);
        short8 b1 = *(const short8*)(lb + 1024);
        short8 b2 = *(const short8*)(lb + 2048);
        short8 b3 = *(const short8*)(lb + 3072);
        MFMA(acc[0], a0, b0); MFMA(acc[1], a0, b1);
        MFMA(acc[2], a0, b2); MFMA(acc[3], a0, b3);
      }
#pragma unroll
      for (int k = 28; k < 32; ++k) {
        short8 a0 = pa[k & 3];
        const unsigned char* lb = lbbase + (size_t)k * 4096;
        short8 b0 = *(const short8*)(lb);
        short8 b1 = *(const short8*)(lb + 1024);
        short8 b2 = *(const short8*)(lb + 2048);
        short8 b3 = *(const short8*)(lb + 3072);
        MFMA(acc[0], a0, b0); MFMA(acc[1], a0, b1);
        MFMA(acc[2], a0, b2); MFMA(acc[3], a0, b3);
      }
    }

    // ---- gate combine in registers; coherent h stores (16 rows x 16 cols per wave) ----
    {
      const int q2 = jh * 2 + (c >> 3);   // within-unit col chunk
      const int e2 = c & 7;
      const size_t ob = ((size_t)(((p ^ 1) * 2 + dir) * 32 + jt) * 16 + bt0) * 512;
      us* hd = Hf + ob + (size_t)(16 * q2) * 8 + e2;
#pragma unroll
      for (int rg = 0; rg < 4; ++rg) {
        float gi = acc[0][rg], gf = acc[1][rg];
        float go = acc[2][rg], gc = acc[3][rg];
        float cn = sigf(gf) * c_reg[rg] + sigf(gi) * tanh_(gc);
        c_reg[rg] = cn;
        __hip_atomic_store(hd + (size_t)(q * 4 + rg) * 8, f2bf(sigf(go) * tanh_(cn)),
                           __ATOMIC_RELAXED, __HIP_MEMORY_SCOPE_AGENT);
      }
    }
    asm volatile("s_waitcnt vmcnt(0)" ::: "memory");
    __syncthreads();
    if (tid == 0)
      __hip_atomic_store(my_slot, (unsigned)(s + 1), __ATOMIC_RELAXED, __HIP_MEMORY_SCOPE_AGENT);
  }
}

// ---------------- Phase 4: logits + softmax, one block per batch row ----------------
__global__ void final_softmax(const us* __restrict__ Hf,  // buf 0
                              const float* __restrict__ Whq,
                              const float* __restrict__ bq,
                              float* __restrict__ out) {
  __shared__ float red[4][10];
  const int b = blockIdx.x;
  const int tid = threadIdx.x;
  float acc[10];
#pragma unroll
  for (int qq = 0; qq < 10; ++qq) acc[qq] = 0.f;
#pragma unroll
  for (int u = 0; u < 4; ++u) {
    int j = tid * 4 + u;
    int kt = j >> 5, q2 = (j & 31) >> 3, e = j & 7;
    size_t idx = (((size_t)kt * 16 + (b >> 4)) * 512) + ((size_t)((b & 15) + 16 * q2)) * 8 + e;
    float xv = bf2f(Hf[idx]) + bf2f(Hf[(size_t)32 * 16 * 512 + idx]);
#pragma unroll
    for (int qq = 0; qq < 10; ++qq) acc[qq] += xv * Whq[j * 10 + qq];
  }
#pragma unroll
  for (int qq = 0; qq < 10; ++qq)
#pragma unroll
    for (int off = 32; off; off >>= 1) acc[qq] += __shfl_down(acc[qq], off, 64);
  if ((tid & 63) == 0)
#pragma unroll
    for (int qq = 0; qq < 10; ++qq) red[tid >> 6][qq] = acc[qq];
  __syncthreads();
  if (tid == 0) {
    float t[10];
#pragma unroll
    for (int qq = 0; qq < 10; ++qq)
      t[qq] = red[0][qq] + red[1][qq] + red[2][qq] + red[3][qq] + bq[qq];
    float mx = t[0];
#pragma unroll
    for (int qq = 1; qq < 10; ++qq) mx = fmaxf(mx, t[qq]);
    float sum = 0.f;
#pragma unroll
    for (int qq = 0; qq < 10; ++qq) { t[qq] = __expf(t[qq] - mx); sum += t[qq]; }
    float inv = 1.0f / sum;
#pragma unroll
    for (int qq = 0; qq < 10; ++qq) out[b * 10 + qq] = t[qq] * inv;
  }
}

extern "C" void kernel_launch(void* const* d_in, const int* in_sizes, int n_in,
                              void* d_out, int out_size, void* d_ws, size_t ws_size,
                              hipStream_t stream) {
  const int*   inputs = (const int*)d_in[0];
  const float* emb    = (const float*)d_in[1];
  const float* Wx_f   = (const float*)d_in[2];
  const float* Wh_f   = (const float*)d_in[3];
  const float* b_f    = (const float*)d_in[4];
  const float* Wx_b   = (const float*)d_in[5];
  const float* Wh_b   = (const float*)d_in[6];
  const float* b_b    = (const float*)d_in[7];
  const float* W_hq   = (const float*)d_in[8];
  const float* b_q    = (const float*)d_in[9];
  float* out = (float*)d_out;

  char* ws = (char*)d_ws;
  us* Xf  = (us*)ws;                              // 64 MiB
  us* Wxp = (us*)(ws + (64ull << 20));            //  8 MiB
  us* Whp = (us*)(ws + (72ull << 20));            // 16 MiB
  us* Hf  = (us*)(ws + (88ull << 20));            //  2 MiB
  unsigned int* slt = (unsigned int*)(ws + (90ull << 20));  // 16 KiB

  hipMemsetAsync(Hf, 0, (size_t)2 * 2 * 32 * 16 * 512 * sizeof(us), stream);
  hipMemsetAsync(slt, 0, 4 * 64 * 16 * sizeof(unsigned int), stream);

  gather_embed<<<4096, 256, 0, stream>>>(inputs, emb, Xf);
  pack_w<<<6144, 256, 0, stream>>>(Wx_f, Wh_f, Wx_b, Wh_b, Wxp, Whp);

  hipFuncSetAttribute((const void*)lstm_main,
                      hipFuncAttributeMaxDynamicSharedMemorySize, LDS_BYTES);

  const us* xf_p = Xf;
  const us* wxp_p = Wxp;
  const us* whp_p = Whp;
  const float* bf_p = b_f;
  const float* bb_p = b_b;
  us* hf_p = Hf;
  unsigned int* slt_p = slt;
  void* kargs[] = { (void*)&xf_p, (void*)&wxp_p, (void*)&whp_p, (void*)&bf_p,
                    (void*)&bb_p, (void*)&hf_p, (void*)&slt_p };
  hipLaunchCooperativeKernel((void*)lstm_main, dim3(256), dim3(512), kargs, LDS_BYTES, stream);

  // final h (after step 256) lives in buf 0
  final_softmax<<<256, 256, 0, stream>>>(Hf, W_hq, b_q, out);
}

// Round 9
// 4586.064 us; speedup vs baseline: 22.3890x; 1.0279x over previous
//
#include <hip/hip_runtime.h>

#define S_LEN 256
#define BATCH 256
#define EDIM 512
#define HDIM 1024
#define LDS_BYTES 131072   // FULL Wh slice: 32 hk x 4 gates x 1 KB = 128 KB

typedef short short8 __attribute__((ext_vector_type(8)));
typedef float f32x4 __attribute__((ext_vector_type(4)));
typedef unsigned long long u64;
typedef unsigned short us;

__device__ __forceinline__ us f2bf(float f) {
  unsigned u = __float_as_uint(f);
  u = u + 0x7FFFu + ((u >> 16) & 1u);   // RNE
  return (us)(u >> 16);
}
__device__ __forceinline__ float bf2f(us s) {
  return __uint_as_float(((unsigned)s) << 16);
}
__device__ __forceinline__ float sigf(float x) { return 1.0f / (1.0f + __expf(-x)); }
__device__ __forceinline__ float tanh_(float x) { return 2.0f / (1.0f + __expf(-2.0f * x)) - 1.0f; }

#define MFMA(d, a, b) d = __builtin_amdgcn_mfma_f32_16x16x32_bf16(a, b, d, 0, 0, 0)

// Coherent (agent/MALL) 16B frag load: two 8B agent-scope relaxed atomic loads (R0-proven).
__device__ __forceinline__ short8 load_hfrag(const us* p) {
  union { u64 d[2]; short8 v; } u;
  u.d[0] = __hip_atomic_load((const u64*)p,       __ATOMIC_RELAXED, __HIP_MEMORY_SCOPE_AGENT);
  u.d[1] = __hip_atomic_load((const u64*)(p + 4), __ATOMIC_RELAXED, __HIP_MEMORY_SCOPE_AGENT);
  return u.v;
}
__device__ __forceinline__ short8 ldf(const us* p) {  // plain 16B frag load
  union { uint4 d; short8 v; } u;
  u.d = *(const uint4*)p;
  return u.v;
}

// All frag units are LANE-LINEAR: unit = 512 shorts (1 KB); lane l's 16 bytes at l*16.

// ---------------- Phase 1: gather -> Xf[s][kt16][btile16][512] ----------------
__global__ void gather_embed(const int* __restrict__ inputs, const float* __restrict__ emb,
                             us* __restrict__ Xf) {
  int T = blockIdx.x * 256 + threadIdx.x;   // 1,048,576
  int kt = T & 15;
  int b  = (T >> 4) & 255;
  int s  = T >> 12;
  int vid = inputs[b * S_LEN + s];
  const float* src = emb + (size_t)vid * EDIM + kt * 32;
  int c = b & 15;
  us* ub = Xf + ((size_t)(s * 16 + kt) * 16 + (b >> 4)) * 512;
#pragma unroll
  for (int q = 0; q < 4; ++q) {
    float4 v0 = *(const float4*)(src + q * 8);
    float4 v1 = *(const float4*)(src + q * 8 + 4);
    us o[8] = { f2bf(v0.x), f2bf(v0.y), f2bf(v0.z), f2bf(v0.w),
                f2bf(v1.x), f2bf(v1.y), f2bf(v1.z), f2bf(v1.w) };
    *(uint4*)(ub + (size_t)(c + 16 * q) * 8) = *(const uint4*)o;
  }
}

// ---------------- Phase 2: pack W into lane-linear frag units ----------------
__global__ void pack_w(const float* __restrict__ Wx_f, const float* __restrict__ Wh_f,
                       const float* __restrict__ Wx_b, const float* __restrict__ Wh_b,
                       us* __restrict__ Wxp, us* __restrict__ Whp) {
  int T = blockIdx.x * 256 + threadIdx.x;   // 1,572,864
  int c = T & 15;
  int q = (T >> 4) & 3;
  int t = (T >> 6) & 7;
  int r = T >> 9;                           // 0..3071
  int kit = r % 48;
  int jbd = r / 48;
  int jb  = jbd & 31;
  int dir = jbd >> 5;
  int g = t >> 1, h16 = t & 1;
  int n = g * 1024 + jb * 32 + h16 * 16 + c;
  const float* W; int k0;
  if (kit < 16) { W = dir ? Wx_b : Wx_f; k0 = kit * 32 + q * 8; }
  else          { W = dir ? Wh_b : Wh_f; k0 = (kit - 16) * 32 + q * 8; }
  us o[8];
#pragma unroll
  for (int e = 0; e < 8; ++e) o[e] = f2bf(W[(size_t)(k0 + e) * 4096 + n]);
  us* dst;
  if (kit < 16) dst = Wxp + (((size_t)(dir * 32 + jb) * 16 + kit) * 8 + t) * 512;
  else          dst = Whp + (((size_t)(dir * 32 + jb) * 32 + (kit - 16)) * 8 + t) * 512;
  *(uint4*)(dst + (size_t)(c + 16 * q) * 8) = *(const uint4*)o;
}

// ---------------- Phase 3: persistent BiLSTM, per-WAVE rings ----------------
// R8 tiling (256 blocks = dir2 x mq2 x J64; Wh slice fully LDS; wave w owns
// btile mq*8+w). NEW: the step protocol is per-wave, not per-block. Wave w of
// block (g,J') depends only on wave w of blocks (g, all J) -> 32 independent
// rings of 64 waves. No __syncthreads in the loop; per-wave poll of 64 dense
// slots [g][w][J]; h-tile stores shuffle-packed into 8B agent atomics; per-wave
// vmcnt flush then per-wave publish. MFMA order identical -> bit-identical.
__global__ __launch_bounds__(512, 1) void lstm_main(
    const us* __restrict__ Xf,
    const us* __restrict__ Wxp,
    const us* __restrict__ Whp,
    const float* __restrict__ bias_f,
    const float* __restrict__ bias_b,
    us* __restrict__ Hf,                    // [buf2][dir2][kt32][btile16][512]
    unsigned int* __restrict__ slots)       // [group4][wave8][J64] (4B dense)
{
  extern __shared__ __align__(16) unsigned char smem[];

  const int bx  = blockIdx.x;
  const int dir = bx & 1;
  const int mq  = (bx >> 1) & 1;
  const int J   = bx >> 2;            // 0..63
  const int jh  = J & 1;              // half within kt unit (cols jh*16..+16)
  const int jt  = J >> 1;             // kt unit (0..31)

  const int tid  = threadIdx.x;
  const int wave = tid >> 6;          // 0..7 -> btile
  const int lane = tid & 63;
  const int c    = lane & 15;
  const int q    = lane >> 4;
  const int e    = c & 7;             // within 8-lane pack group
  const int ch   = c >> 3;            // col-chunk half within the 16 cols
  const int lofs = lane * 8;          // shorts (16 B)

  // LDS fill: Wh units for (dir, jt, jh), all 32 hk x 4 gates, layout [hk][g][1KB]
  {
    const uint4* W4 = (const uint4*)Whp;
    for (int i = tid; i < 8192; i += 512) {
      int within = i & 63;
      int g  = (i >> 6) & 3;
      int hk = i >> 8;
      size_t src = ((((size_t)(dir * 32 + jt) * 32 + hk) * 8) + (g * 2 + jh)) * 64 + within;
      *(uint4*)(smem + (size_t)i * 16) = W4[src];
    }
  }
  const float* bias = dir ? bias_b : bias_f;
  const int j = J * 16 + c;
  float bg[4];
#pragma unroll
  for (int g = 0; g < 4; ++g) bg[g] = bias[g * HDIM + j];
  __syncthreads();   // LDS ready; ONLY barrier in the kernel

  // per-wave ring: 64 members (all J), dense 4B slots
  unsigned int* ring    = slots + (((dir * 2 + mq) * 8 + wave) * 64);
  unsigned int* my_slot = ring + J;

  const int bt0 = mq * 8 + wave;      // this wave's single btile
  const us* xu_base = Xf + (size_t)bt0 * 512 + lofs;
  const us* wxu = Wxp + ((size_t)(dir * 32 + jt) * 16) * 8 * 512 + (size_t)jh * 512 + lofs;
  const unsigned char* lbbase = smem + (size_t)lane * 16;

  float c_reg[4] = {0.f, 0.f, 0.f, 0.f};

  for (int s = 0; s < S_LEN; ++s) {
    const int sx = dir ? (S_LEN - 1 - s) : s;
    const int p  = s & 1;

    f32x4 acc[4];
#pragma unroll
    for (int g = 0; g < 4; ++g)
      acc[g] = (f32x4){bg[g], bg[g], bg[g], bg[g]};

    // ---- x-part (no h dependency; overlaps producers' publish latency) ----
    {
      const us* xu = xu_base + (size_t)sx * (16 * 16 * 512);
#pragma unroll 4
      for (int k = 0; k < 16; ++k) {
        short8 a0 = ldf(xu + (size_t)k * 8192);
        const us* wb = wxu + (size_t)k * 4096;
        short8 b0 = ldf(wb);
        short8 b1 = ldf(wb + 1024);
        short8 b2 = ldf(wb + 2048);
        short8 b3 = ldf(wb + 3072);
        MFMA(acc[0], a0, b0); MFMA(acc[1], a0, b1);
        MFMA(acc[2], a0, b2); MFMA(acc[3], a0, b3);
      }
    }

    // ---- per-wave poll: 64 lanes read the 64 producer slots of own ring ----
    if (s > 0) {
      const unsigned int* sl = ring + lane;
      for (;;) {
        unsigned v = __hip_atomic_load(sl, __ATOMIC_RELAXED, __HIP_MEMORY_SCOPE_AGENT);
        if (!__any(v < (unsigned)s)) break;
        __builtin_amdgcn_s_sleep(1);
      }
      asm volatile("" ::: "memory");
    }

    // ---- h-part: A coherent from Hf (proven depth-4 ring); B entirely from LDS ----
    {
      const us* hu = Hf + (((size_t)(p * 2 + dir) * 32) * 16 + bt0) * 512 + lofs;
      short8 pa[4];
#pragma unroll
      for (int i = 0; i < 4; ++i) pa[i] = load_hfrag(hu + (size_t)i * 8192);
#pragma unroll 4
      for (int k = 0; k < 28; ++k) {
        short8 a0 = pa[k & 3];
        pa[k & 3] = load_hfrag(hu + (size_t)(k + 4) * 8192);
        const unsigned char* lb = lbbase + (size_t)k * 4096;
        short8 b0 = *(const short8*)(lb);
        short8 b1 = *(const short8*)(lb + 1024);
        short8 b2 = *(const short8*)(lb + 2048);
        short8 b3 = *(const short8*)(lb + 3072);
        MFMA(acc[0], a0, b0); MFMA(acc[1], a0, b1);
        MFMA(acc[2], a0, b2); MFMA(acc[3], a0, b3);
      }
#pragma unroll
      for (int k = 28; k < 32; ++k) {
        short8 a0 = pa[k & 3];
        const unsigned char* lb = lbbase + (size_t)k * 4096;
        short8 b0 = *(const short8*)(lb);
        short8 b1 = *(const short8*)(lb + 1024);
        short8 b2 = *(const short8*)(lb + 2048);
        short8 b3 = *(const short8*)(lb + 3072);
        MFMA(acc[0], a0, b0); MFMA(acc[1], a0, b1);
        MFMA(acc[2], a0, b2); MFMA(acc[3], a0, b3);
      }
    }

    // ---- gates; shuffle-pack h into 16B chunks; 8B agent-atomic stores ----
    {
      const size_t ob = ((size_t)(((p ^ 1) * 2 + dir) * 32 + jt) * 16 + bt0) * 512;
      us* hb = Hf + ob;
#pragma unroll
      for (int rg = 0; rg < 4; ++rg) {
        float gi = acc[0][rg], gf = acc[1][rg];
        float go = acc[2][rg], gc = acc[3][rg];
        float cn = sigf(gf) * c_reg[rg] + sigf(gi) * tanh_(gc);
        c_reg[rg] = cn;
        unsigned a = (unsigned)f2bf(sigf(go) * tanh_(cn));
        // round 1 (xor 1): dword = even_e | odd_e<<16
        unsigned p1 = __shfl_xor(a, 1, 64);
        unsigned d  = (e & 1) ? ((p1 & 0xffffu) | (a << 16))
                              : ((a  & 0xffffu) | (p1 << 16));
        // round 2 (xor 2): [lo2,hi2] = dwords (e01, e23) of own 4-group
        unsigned o2  = __shfl_xor(d, 2, 64);
        unsigned lo2 = (e & 2) ? o2 : d;
        unsigned hi2 = (e & 2) ? d  : o2;
        // round 3 (xor 4): full 16B chunk [e01,e23,e45,e67]
        unsigned ol = __shfl_xor(lo2, 4, 64);
        unsigned oh = __shfl_xor(hi2, 4, 64);
        u64 w0 = (e & 4) ? (((u64)oh  << 32) | ol ) : (((u64)hi2 << 32) | lo2);
        u64 w1 = (e & 4) ? (((u64)hi2 << 32) | lo2) : (((u64)oh  << 32) | ol );
        if (e == 0) {
          // chunk (row r=q*4+rg, col-half q2=jh*2+ch) -> shorts (r+16*q2)*8..+8
          u64* dst = (u64*)(hb + (size_t)((q * 4 + rg) + 16 * (jh * 2 + ch)) * 8);
          __hip_atomic_store(dst,     w0, __ATOMIC_RELAXED, __HIP_MEMORY_SCOPE_AGENT);
          __hip_atomic_store(dst + 1, w1, __ATOMIC_RELAXED, __HIP_MEMORY_SCOPE_AGENT);
        }
      }
    }
    // per-wave flush (vmcnt is per-wave), then per-wave publish
    asm volatile("s_waitcnt vmcnt(0)" ::: "memory");
    if (lane == 0)
      __hip_atomic_store(my_slot, (unsigned)(s + 1), __ATOMIC_RELAXED, __HIP_MEMORY_SCOPE_AGENT);
  }
}

// ---------------- Phase 4: logits + softmax, one block per batch row ----------------
__global__ void final_softmax(const us* __restrict__ Hf,  // buf 0
                              const float* __restrict__ Whq,
                              const float* __restrict__ bq,
                              float* __restrict__ out) {
  __shared__ float red[4][10];
  const int b = blockIdx.x;
  const int tid = threadIdx.x;
  float acc[10];
#pragma unroll
  for (int qq = 0; qq < 10; ++qq) acc[qq] = 0.f;
#pragma unroll
  for (int u = 0; u < 4; ++u) {
    int j = tid * 4 + u;
    int kt = j >> 5, q2 = (j & 31) >> 3, e = j & 7;
    size_t idx = (((size_t)kt * 16 + (b >> 4)) * 512) + ((size_t)((b & 15) + 16 * q2)) * 8 + e;
    float xv = bf2f(Hf[idx]) + bf2f(Hf[(size_t)32 * 16 * 512 + idx]);
#pragma unroll
    for (int qq = 0; qq < 10; ++qq) acc[qq] += xv * Whq[j * 10 + qq];
  }
#pragma unroll
  for (int qq = 0; qq < 10; ++qq)
#pragma unroll
    for (int off = 32; off; off >>= 1) acc[qq] += __shfl_down(acc[qq], off, 64);
  if ((tid & 63) == 0)
#pragma unroll
    for (int qq = 0; qq < 10; ++qq) red[tid >> 6][qq] = acc[qq];
  __syncthreads();
  if (tid == 0) {
    float t[10];
#pragma unroll
    for (int qq = 0; qq < 10; ++qq)
      t[qq] = red[0][qq] + red[1][qq] + red[2][qq] + red[3][qq] + bq[qq];
    float mx = t[0];
#pragma unroll
    for (int qq = 1; qq < 10; ++qq) mx = fmaxf(mx, t[qq]);
    float sum = 0.f;
#pragma unroll
    for (int qq = 0; qq < 10; ++qq) { t[qq] = __expf(t[qq] - mx); sum += t[qq]; }
    float inv = 1.0f / sum;
#pragma unroll
    for (int qq = 0; qq < 10; ++qq) out[b * 10 + qq] = t[qq] * inv;
  }
}

extern "C" void kernel_launch(void* const* d_in, const int* in_sizes, int n_in,
                              void* d_out, int out_size, void* d_ws, size_t ws_size,
                              hipStream_t stream) {
  const int*   inputs = (const int*)d_in[0];
  const float* emb    = (const float*)d_in[1];
  const float* Wx_f   = (const float*)d_in[2];
  const float* Wh_f   = (const float*)d_in[3];
  const float* b_f    = (const float*)d_in[4];
  const float* Wx_b   = (const float*)d_in[5];
  const float* Wh_b   = (const float*)d_in[6];
  const float* b_b    = (const float*)d_in[7];
  const float* W_hq   = (const float*)d_in[8];
  const float* b_q    = (const float*)d_in[9];
  float* out = (float*)d_out;

  char* ws = (char*)d_ws;
  us* Xf  = (us*)ws;                              // 64 MiB
  us* Wxp = (us*)(ws + (64ull << 20));            //  8 MiB
  us* Whp = (us*)(ws + (72ull << 20));            // 16 MiB
  us* Hf  = (us*)(ws + (88ull << 20));            //  2 MiB
  unsigned int* slt = (unsigned int*)(ws + (90ull << 20));  // 8 KiB

  hipMemsetAsync(Hf, 0, (size_t)2 * 2 * 32 * 16 * 512 * sizeof(us), stream);
  hipMemsetAsync(slt, 0, 4 * 8 * 64 * sizeof(unsigned int), stream);

  gather_embed<<<4096, 256, 0, stream>>>(inputs, emb, Xf);
  pack_w<<<6144, 256, 0, stream>>>(Wx_f, Wh_f, Wx_b, Wh_b, Wxp, Whp);

  hipFuncSetAttribute((const void*)lstm_main,
                      hipFuncAttributeMaxDynamicSharedMemorySize, LDS_BYTES);

  const us* xf_p = Xf;
  const us* wxp_p = Wxp;
  const us* whp_p = Whp;
  const float* bf_p = b_f;
  const float* bb_p = b_b;
  us* hf_p = Hf;
  unsigned int* slt_p = slt;
  void* kargs[] = { (void*)&xf_p, (void*)&wxp_p, (void*)&whp_p, (void*)&bf_p,
                    (void*)&bb_p, (void*)&hf_p, (void*)&slt_p };
  hipLaunchCooperativeKernel((void*)lstm_main, dim3(256), dim3(512), kargs, LDS_BYTES, stream);

  // final h (after step 256) lives in buf 0
  final_softmax<<<256, 256, 0, stream>>>(Hf, W_hq, b_q, out);
}